// Round 1
// baseline (590.065 us; speedup 1.0000x reference)
//
#include <hip/hip_runtime.h>
#include <hip/hip_bf16.h>
#include <math.h>

// Problem constants: B=32, U=4096, K=4, N=2, K2=2, STRIDE=2048, UN=2048
// ws: (2, 4, 2048, 8192) f32 = 512 MB  -> the traffic floor
// GEMM per j: (32 x 8192) @ (8192 x 8192)
//
// d_out layout (flat, return order):
//   x_out  [0,      131072)   (32,4096)
//   new_hs [131072, 393216)   (2,2,32,2048)
//   new_c  [393216, 917504)   (2,4,32,2048)
//
// d_ws layout:
//   in_t    at byte 0        : 2*8192*32 f32 = 2 MB   (in_t[j][kkd][b])
//   partial at byte 2 MB     : 1024*2048 f32 = 8 MB   (partial[(j*128+ft)*4+s][b*64+fl])

#define IN_T_ELEMS (2 * 8192 * 32)

__global__ __launch_bounds__(256) void transpose_in(const float* __restrict__ x,
                                                    const float* __restrict__ hs,
                                                    float* __restrict__ in_t) {
    int tid = blockIdx.x * 256 + threadIdx.x;   // [0, 524288)
    int b   = tid & 31;
    int kkd = (tid >> 5) & 8191;
    int j   = tid >> 18;
    float v;
    if (kkd < 4096) {
        // kk<2: x_chunks[b][kk][d] = x[b][kk*2048+d] = x[b][kkd]
        v = x[b * 4096 + kkd];
    } else {
        int kk = kkd >> 11;       // 2 or 3
        int d  = kkd & 2047;
        // hs[j][kk-2][b][d], hs shape (2,2,32,2048)
        v = hs[((j * 2 + (kk - 2)) * 32 + b) * 2048 + d];
    }
    in_t[tid] = v;
}

// Grid: 1024 blocks = 2 (j) x 128 (f-tile of 64) x 4 (K-chunk s). Block = 256 (4 waves).
// Wave w handles kkd in [s*2048 + w*512, +512), lane owns one f column, acc[32] over b.
__global__ __launch_bounds__(256) void gemm_partial(const float* __restrict__ in_t,
                                                    const float* __restrict__ wsm,
                                                    float* __restrict__ partial) {
    int lin  = blockIdx.x;
    int s    = lin & 3;
    int ft   = (lin >> 2) & 127;
    int j    = lin >> 9;
    int w    = threadIdx.x >> 6;
    int lane = threadIdx.x & 63;
    int f    = ft * 64 + lane;
    int k0   = s * 2048 + w * 512;

    const float* __restrict__ wp = wsm + ((size_t)j * 8192 + k0) * 8192 + f;
    const float* __restrict__ ip = in_t + ((size_t)j * 8192 + k0) * 32;

    float acc[32];
#pragma unroll
    for (int b = 0; b < 32; ++b) acc[b] = 0.f;

    for (int t = 0; t < 512; t += 4) {
        float wv[4];
#pragma unroll
        for (int u = 0; u < 4; ++u) wv[u] = wp[(size_t)u * 8192];
#pragma unroll
        for (int u = 0; u < 4; ++u) {
#pragma unroll
            for (int b = 0; b < 32; ++b)
                acc[b] = fmaf(ip[u * 32 + b], wv[u], acc[b]);
        }
        wp += (size_t)4 * 8192;
        ip += 4 * 32;
    }

    // Cross-wave reduction in LDS: red[w][b][lane]
    __shared__ float red[4][32][64];   // 32 KB
#pragma unroll
    for (int b = 0; b < 32; ++b) red[w][b][lane] = acc[b];
    __syncthreads();

    // 256 threads each produce 8 of the 2048 block outputs (b*64 + fl), coalesced
    int base = threadIdx.x * 8;
#pragma unroll
    for (int q = 0; q < 8; ++q) {
        int idx = base + q;
        int b   = idx >> 6;
        int fl  = idx & 63;
        float sum = red[0][b][fl] + red[1][b][fl] + red[2][b][fl] + red[3][b][fl];
        partial[(size_t)((j * 128 + ft) * 4 + s) * 2048 + idx] = sum;
    }
}

__device__ __forceinline__ float sigmoidf_(float v) { return 1.f / (1.f + expf(-v)); }

// 131072 threads: tid -> (j, b, un)
__global__ __launch_bounds__(256) void epilogue(const float* __restrict__ partial,
                                                const float* __restrict__ cs,
                                                float* __restrict__ out) {
    int tid = blockIdx.x * 256 + threadIdx.x;
    int un  = tid & 2047;
    int b   = (tid >> 11) & 31;
    int j   = tid >> 16;

    float g4[4];
#pragma unroll
    for (int gate = 0; gate < 4; ++gate) {
        int f  = gate * 2048 + un;
        int ft = f >> 6;
        int fl = f & 63;
        const float* p = partial + (size_t)(j * 128 + ft) * 4 * 2048 + b * 64 + fl;
        g4[gate] = p[0] + p[2048] + p[4096] + p[6144];
    }
    float iv = sigmoidf_(g4[0]);
    float fv = sigmoidf_(g4[1]);
    float gv = tanhf(g4[2]);
    float ov = sigmoidf_(g4[3]);
    float ig = iv * gv;

#pragma unroll
    for (int kk = 0; kk < 4; ++kk) {
        float c_old = cs[((j * 4 + kk) * 32 + b) * 2048 + un];
        float c_new = fv * c_old + ig;
        float h     = ov * tanhf(c_new);
        out[393216 + ((j * 4 + kk) * 32 + b) * 2048 + un] = c_new;   // new_c
        if (kk == 0) {
            out[b * 4096 + j * 2048 + un] = h;                       // x_out
        }
        if (kk == j + 2) {
            // new_hs[jj][j][b][un] = h for jj in {0,1}
            out[131072 + ((0 * 2 + j) * 32 + b) * 2048 + un] = h;
            out[131072 + ((1 * 2 + j) * 32 + b) * 2048 + un] = h;
        }
    }
}

extern "C" void kernel_launch(void* const* d_in, const int* in_sizes, int n_in,
                              void* d_out, int out_size, void* d_ws, size_t ws_size,
                              hipStream_t stream) {
    const float* x   = (const float*)d_in[0];
    const float* hs  = (const float*)d_in[1];
    const float* cs  = (const float*)d_in[2];
    const float* wsm = (const float*)d_in[3];
    float* out = (float*)d_out;

    float* in_t    = (float*)d_ws;                       // 2 MB
    float* partial = (float*)((char*)d_ws + (size_t)IN_T_ELEMS * 4);  // 8 MB

    transpose_in<<<524288 / 256, 256, 0, stream>>>(x, hs, in_t);
    gemm_partial<<<1024, 256, 0, stream>>>(in_t, wsm, partial);
    epilogue<<<131072 / 256, 256, 0, stream>>>(partial, cs, out);
}

// Round 2
// 217.567 us; speedup vs baseline: 2.7121x; 2.7121x over previous
//
#include <hip/hip_runtime.h>
#include <hip/hip_bf16.h>
#include <math.h>

// Problem constants: B=32, U=4096, K=4, N=2, K2=2, STRIDE=2048, UN=2048
// ws: (2, 4, 2048, 8192) f32 = 512 MB  -> the traffic floor
// GEMM per j: (32 x 8192) @ (8192 x 8192), f32 vector-FMA (no fp32 MFMA on CDNA4)
//
// d_out layout (flat, return order):
//   x_out  [0,      131072)   (32,4096)
//   new_hs [131072, 393216)   (2,2,32,2048)
//   new_c  [393216, 917504)   (2,4,32,2048)
//
// d_ws layout:
//   in_t    at byte 0    : 2*8192*32 f32 = 2 MB     (in_t[j][k][b])
//   partial at byte 2 MB : 2*8*32*8192 f32 = 16.8 MB (partial[j][s][b][f])

#define IN_T_ELEMS (2 * 8192 * 32)

__global__ __launch_bounds__(256) void transpose_in(const float* __restrict__ x,
                                                    const float* __restrict__ hs,
                                                    float* __restrict__ in_t) {
    int tid = blockIdx.x * 256 + threadIdx.x;   // [0, 524288)
    int b   = tid & 31;
    int kkd = (tid >> 5) & 8191;
    int j   = tid >> 18;
    float v;
    if (kkd < 4096) {
        v = x[b * 4096 + kkd];                       // x_chunks[b][kk][d] = x[b][kkd]
    } else {
        int kk = kkd >> 11;                          // 2 or 3
        int d  = kkd & 2047;
        v = hs[((j * 2 + (kk - 2)) * 32 + b) * 2048 + d];   // hs (2,2,32,2048)
    }
    in_t[tid] = v;
}

// Grid: 512 blocks = 2 (j) x 32 (f-tile of 256) x 8 (K-chunk s). Block = 256 (4 waves).
// Wave w owns batches [w*8, w*8+8); lane owns 4 consecutive f (float4 ws loads).
// All 4 waves read the same ws tile (rows k0..k0+1024, 256 f) -> L1/L2 reuse.
// in_t reads are wave-uniform (readfirstlane on w) -> scalar s_load, values in SGPRs.
__global__ __launch_bounds__(256) void gemm_partial(const float* __restrict__ in_t,
                                                    const float* __restrict__ wsm,
                                                    float* __restrict__ partial) {
    int lin = blockIdx.x;
    int s   = lin & 7;
    int ft  = (lin >> 3) & 31;
    int j   = lin >> 8;
    int w    = __builtin_amdgcn_readfirstlane((int)(threadIdx.x >> 6));
    int lane = threadIdx.x & 63;
    int f0   = ft * 256 + lane * 4;
    int k0   = s * 1024;

    const float* __restrict__ wp = wsm + ((size_t)j * 8192 + k0) * 8192 + f0;
    const float* __restrict__ ip = in_t + (size_t)(j * 8192 + k0) * 32 + w * 8;

    float acc[8][4];
#pragma unroll
    for (int b = 0; b < 8; ++b)
#pragma unroll
        for (int q = 0; q < 4; ++q) acc[b][q] = 0.f;

    for (int t = 0; t < 1024; t += 8) {
        float4 wv[8];
#pragma unroll
        for (int u = 0; u < 8; ++u)
            wv[u] = *(const float4*)(wp + (size_t)u * 8192);
        // wave-uniform input values -> SGPRs via s_load
        float av[8][8];
#pragma unroll
        for (int u = 0; u < 8; ++u)
#pragma unroll
            for (int b = 0; b < 8; ++b)
                av[u][b] = ip[u * 32 + b];
#pragma unroll
        for (int u = 0; u < 8; ++u)
#pragma unroll
            for (int b = 0; b < 8; ++b) {
                acc[b][0] = fmaf(av[u][b], wv[u].x, acc[b][0]);
                acc[b][1] = fmaf(av[u][b], wv[u].y, acc[b][1]);
                acc[b][2] = fmaf(av[u][b], wv[u].z, acc[b][2]);
                acc[b][3] = fmaf(av[u][b], wv[u].w, acc[b][3]);
            }
        wp += (size_t)8 * 8192;
        ip += 8 * 32;
    }

    // partial[j][s][b][f]: coalesced float4 stores
    size_t pbase = ((size_t)((j * 8 + s) * 32 + w * 8)) * 8192 + f0;
#pragma unroll
    for (int b = 0; b < 8; ++b)
        *(float4*)(partial + pbase + (size_t)b * 8192) = *(const float4*)acc[b];
}

__device__ __forceinline__ float sigmoidf_(float v) { return 1.f / (1.f + expf(-v)); }

// 131072 threads: tid -> (j, b, un)
__global__ __launch_bounds__(256) void epilogue(const float* __restrict__ partial,
                                                const float* __restrict__ cs,
                                                float* __restrict__ out) {
    int tid = blockIdx.x * 256 + threadIdx.x;
    int un  = tid & 2047;
    int b   = (tid >> 11) & 31;
    int j   = tid >> 16;

    float g4[4];
#pragma unroll
    for (int gate = 0; gate < 4; ++gate) {
        int f = gate * 2048 + un;
        float sum = 0.f;
#pragma unroll
        for (int s = 0; s < 8; ++s)
            sum += partial[((size_t)((j * 8 + s) * 32 + b)) * 8192 + f];
        g4[gate] = sum;
    }
    float iv = sigmoidf_(g4[0]);
    float fv = sigmoidf_(g4[1]);
    float gv = tanhf(g4[2]);
    float ov = sigmoidf_(g4[3]);
    float ig = iv * gv;

#pragma unroll
    for (int kk = 0; kk < 4; ++kk) {
        float c_old = cs[((j * 4 + kk) * 32 + b) * 2048 + un];
        float c_new = fv * c_old + ig;
        float h     = ov * tanhf(c_new);
        out[393216 + ((j * 4 + kk) * 32 + b) * 2048 + un] = c_new;   // new_c
        if (kk == 0) {
            out[b * 4096 + j * 2048 + un] = h;                       // x_out
        }
        if (kk == j + 2) {
            // new_hs[jj][j][b][un] = h for jj in {0,1}
            out[131072 + ((0 * 2 + j) * 32 + b) * 2048 + un] = h;
            out[131072 + ((1 * 2 + j) * 32 + b) * 2048 + un] = h;
        }
    }
}

extern "C" void kernel_launch(void* const* d_in, const int* in_sizes, int n_in,
                              void* d_out, int out_size, void* d_ws, size_t ws_size,
                              hipStream_t stream) {
    const float* x   = (const float*)d_in[0];
    const float* hs  = (const float*)d_in[1];
    const float* cs  = (const float*)d_in[2];
    const float* wsm = (const float*)d_in[3];
    float* out = (float*)d_out;

    float* in_t    = (float*)d_ws;                                    // 2 MB
    float* partial = (float*)((char*)d_ws + (size_t)IN_T_ELEMS * 4);  // 16.8 MB

    transpose_in<<<524288 / 256, 256, 0, stream>>>(x, hs, in_t);
    gemm_partial<<<512, 256, 0, stream>>>(in_t, wsm, partial);
    epilogue<<<131072 / 256, 256, 0, stream>>>(partial, cs, out);
}

// Round 3
// 172.383 us; speedup vs baseline: 3.4230x; 1.2621x over previous
//
#include <hip/hip_runtime.h>
#include <hip/hip_bf16.h>
#include <math.h>

// Problem constants: B=32, U=4096, K=4, N=2, K2=2, STRIDE=2048, UN=2048
// ws: (2, 4, 2048, 8192) f32 = 512 MB  -> the traffic floor
// GEMM per j: (32 x 8192) @ (8192 x 8192), f32 vector-FMA (no fp32 MFMA on CDNA4)
//
// d_out layout (flat, return order):
//   x_out  [0,      131072)   (32,4096)
//   new_hs [131072, 393216)   (2,2,32,2048)
//   new_c  [393216, 917504)   (2,4,32,2048)
//
// d_ws layout:
//   in_t    at byte 0    : 2*8192*32 f32 = 2 MB       (in_t[j][k][b])
//   partial at byte 2 MB : 2*16*32*8192 f32 = 33.5 MB (partial[j][s][b][f])

#define IN_T_ELEMS (2 * 8192 * 32)
#define NSPLIT 16

__global__ __launch_bounds__(256) void transpose_in(const float* __restrict__ x,
                                                    const float* __restrict__ hs,
                                                    float* __restrict__ in_t) {
    int tid = blockIdx.x * 256 + threadIdx.x;   // [0, 524288)
    int b   = tid & 31;
    int kkd = (tid >> 5) & 8191;
    int j   = tid >> 18;
    float v;
    if (kkd < 4096) {
        v = x[b * 4096 + kkd];                       // x_chunks[b][kk][d] = x[b][kkd]
    } else {
        int kk = kkd >> 11;                          // 2 or 3
        int d  = kkd & 2047;
        v = hs[((j * 2 + (kk - 2)) * 32 + b) * 2048 + d];   // hs (2,2,32,2048)
    }
    in_t[tid] = v;
}

// Grid: 1024 blocks = 2 (j) x 32 (f-tile of 256) x 16 (K-chunk s). Block = 256 (4 waves).
// 4 blocks/CU -> 4 waves/SIMD. Wave w owns batches [w*8, w*8+8); lane owns 4 consecutive f.
// All 4 waves read the same ws rows (k0..k0+512, 256 f) -> L1/L2 dedup.
// in_t reads are wave-uniform (readfirstlane on w) -> s_load, values live in SGPRs.
// ws loads are register double-buffered (wa/wb ping-pong, static indexing only).
__global__ __launch_bounds__(256, 4) void gemm_partial(const float* __restrict__ in_t,
                                                       const float* __restrict__ wsm,
                                                       float* __restrict__ partial) {
    int lin = blockIdx.x;
    int s   = lin & (NSPLIT - 1);
    int ft  = (lin >> 4) & 31;
    int j   = lin >> 9;
    int w    = __builtin_amdgcn_readfirstlane((int)(threadIdx.x >> 6));
    int lane = threadIdx.x & 63;
    int f0   = ft * 256 + lane * 4;
    int k0   = s * 512;

    const float* __restrict__ wp = wsm + ((size_t)j * 8192 + k0) * 8192 + f0;
    const float* __restrict__ ip = in_t + (size_t)(j * 8192 + k0) * 32 + w * 8;

    float acc[8][4];
#pragma unroll
    for (int b = 0; b < 8; ++b)
#pragma unroll
        for (int q = 0; q < 4; ++q) acc[b][q] = 0.f;

    float4 wa[8], wb[8];
#pragma unroll
    for (int u = 0; u < 8; ++u)
        wa[u] = *(const float4*)(wp + (size_t)u * 8192);
    wp += (size_t)8 * 8192;

#define FMA_BLOCK(WV)                                                  \
    {                                                                  \
        float av[8][8];                                                \
        _Pragma("unroll")                                              \
        for (int u = 0; u < 8; ++u)                                    \
            _Pragma("unroll")                                          \
            for (int b = 0; b < 8; ++b)                                \
                av[u][b] = ip[u * 32 + b];                             \
        _Pragma("unroll")                                              \
        for (int u = 0; u < 8; ++u)                                    \
            _Pragma("unroll")                                          \
            for (int b = 0; b < 8; ++b) {                              \
                acc[b][0] = fmaf(av[u][b], WV[u].x, acc[b][0]);        \
                acc[b][1] = fmaf(av[u][b], WV[u].y, acc[b][1]);        \
                acc[b][2] = fmaf(av[u][b], WV[u].z, acc[b][2]);        \
                acc[b][3] = fmaf(av[u][b], WV[u].w, acc[b][3]);        \
            }                                                          \
        ip += 8 * 32;                                                  \
    }

    for (int t = 0; t < 512; t += 16) {
        // body 1: prefetch rows t+8 into wb, compute rows t from wa
#pragma unroll
        for (int u = 0; u < 8; ++u)
            wb[u] = *(const float4*)(wp + (size_t)u * 8192);
        wp += (size_t)8 * 8192;
        FMA_BLOCK(wa)
        // body 2: prefetch rows t+16 into wa (guarded, uniform branch), compute rows t+8 from wb
        if (t + 16 < 512) {
#pragma unroll
            for (int u = 0; u < 8; ++u)
                wa[u] = *(const float4*)(wp + (size_t)u * 8192);
            wp += (size_t)8 * 8192;
        }
        FMA_BLOCK(wb)
    }
#undef FMA_BLOCK

    // partial[j][s][b][f]: coalesced float4 stores
    size_t pbase = ((size_t)((j * NSPLIT + s) * 32 + w * 8)) * 8192 + f0;
#pragma unroll
    for (int b = 0; b < 8; ++b)
        *(float4*)(partial + pbase + (size_t)b * 8192) = *(const float4*)acc[b];
}

__device__ __forceinline__ float sigmoidf_(float v) { return 1.f / (1.f + expf(-v)); }

// 131072 threads: tid -> (j, b, un)
__global__ __launch_bounds__(256) void epilogue(const float* __restrict__ partial,
                                                const float* __restrict__ cs,
                                                float* __restrict__ out) {
    int tid = blockIdx.x * 256 + threadIdx.x;
    int un  = tid & 2047;
    int b   = (tid >> 11) & 31;
    int j   = tid >> 16;

    float g4[4];
#pragma unroll
    for (int gate = 0; gate < 4; ++gate) {
        int f = gate * 2048 + un;
        float sum = 0.f;
#pragma unroll
        for (int s = 0; s < NSPLIT; ++s)
            sum += partial[((size_t)((j * NSPLIT + s) * 32 + b)) * 8192 + f];
        g4[gate] = sum;
    }
    float iv = sigmoidf_(g4[0]);
    float fv = sigmoidf_(g4[1]);
    float gv = tanhf(g4[2]);
    float ov = sigmoidf_(g4[3]);
    float ig = iv * gv;

#pragma unroll
    for (int kk = 0; kk < 4; ++kk) {
        float c_old = cs[((j * 4 + kk) * 32 + b) * 2048 + un];
        float c_new = fv * c_old + ig;
        float h     = ov * tanhf(c_new);
        out[393216 + ((j * 4 + kk) * 32 + b) * 2048 + un] = c_new;   // new_c
        if (kk == 0) {
            out[b * 4096 + j * 2048 + un] = h;                       // x_out
        }
        if (kk == j + 2) {
            // new_hs[jj][j][b][un] = h for jj in {0,1}
            out[131072 + ((0 * 2 + j) * 32 + b) * 2048 + un] = h;
            out[131072 + ((1 * 2 + j) * 32 + b) * 2048 + un] = h;
        }
    }
}

extern "C" void kernel_launch(void* const* d_in, const int* in_sizes, int n_in,
                              void* d_out, int out_size, void* d_ws, size_t ws_size,
                              hipStream_t stream) {
    const float* x   = (const float*)d_in[0];
    const float* hs  = (const float*)d_in[1];
    const float* cs  = (const float*)d_in[2];
    const float* wsm = (const float*)d_in[3];
    float* out = (float*)d_out;

    float* in_t    = (float*)d_ws;                                    // 2 MB
    float* partial = (float*)((char*)d_ws + (size_t)IN_T_ELEMS * 4);  // 33.5 MB

    transpose_in<<<524288 / 256, 256, 0, stream>>>(x, hs, in_t);
    gemm_partial<<<1024, 256, 0, stream>>>(in_t, wsm, partial);
    epilogue<<<131072 / 256, 256, 0, stream>>>(partial, cs, out);
}